// Round 17
// baseline (231.262 us; speedup 1.0000x reference)
//
#include <hip/hip_runtime.h>

#define N_NODES 40000
#define C_DIM   128
#define K_NBR   16

static constexpr float BETA_F  = 0.11778303565638346f;  // log(1.125)
static constexpr float C1_F    = 0.7939952679092549f;   // (1-ALPHA)*(1-BETA)
static constexpr float C2_F    = 0.08822169643436166f;  // ALPHA*(1-BETA)
static constexpr float INV_DEG = 1.0f / 17.0f;

typedef __attribute__((ext_vector_type(8))) short bf16x8;
typedef __attribute__((ext_vector_type(4))) float f32x4;

__device__ __forceinline__ unsigned pack_bf16x2(float a, float b) {
    unsigned ua = __float_as_uint(a), ub = __float_as_uint(b);
    ua += 0x7fffu + ((ua >> 16) & 1u);     // RNE
    ub += 0x7fffu + ((ub >> 16) & 1u);
    return (ua >> 16) | (ub & 0xffff0000u);
}
__device__ __forceinline__ float bflo(unsigned u) { return __uint_as_float(u << 16); }
__device__ __forceinline__ float bfhi(unsigned u) { return __uint_as_float(u & 0xffff0000u); }

// ---------------------------------------------------------------------------
// Kernel 1 (wprep), grid 128: folded-W bf16 fragment build (1 elem/thread).
// W'[c][o] = c<128 ? (BETA*W1[o][c] + (c==o)*C1) * INV_DEG
//                  : BETA*W2[o][c-128] + (c-128==o)*C2
// ---------------------------------------------------------------------------
__global__ __launch_bounds__(256) void wprep_kernel(
        const float* __restrict__ W1,
        const float* __restrict__ W2,
        unsigned short* __restrict__ WB) {
    const int i = blockIdx.x * 256 + threadIdx.x;  // 0 .. 32767
    const int frag = i >> 9, within = i & 511;
    const int lane = within >> 3, j = within & 7;
    const int otile = frag >> 3, kblk = frag & 7;
    const int o = otile * 16 + (lane & 15);
    const int c = kblk * 32 + ((lane >> 4) << 3) + j;
    float v;
    if (c < 128) {
        v = (BETA_F * W1[o * 128 + c] + (c == o ? C1_F : 0.0f)) * INV_DEG;
    } else {
        const int c2 = c - 128;
        v = BETA_F * W2[o * 128 + c2] + (c2 == o ? C2_F : 0.0f);
    }
    unsigned u = __float_as_uint(v);
    u += 0x7fffu + ((u >> 16) & 1u);
    WB[i] = (unsigned short)(u >> 16);
}

// ---------------------------------------------------------------------------
// Kernel 2 (mono), grid 1250: producer/consumer fusion of prep + fused.
//   Produce: transpose+cast own 32-node tile -> xTb; threadfence (wbl2);
//            release flag[b].
//   Consume: spin (RELAXED agent atomic) on the 17 neighbor-tile flags,
//            then R11's gather (4 quarter passes) + MFMA GEMM + epilogue.
// Deadlock-free by capacity: __launch_bounds__(256,6) -> >=6 blocks/CU
// (VGPR<=85, LDS 18.9KB) -> 1536 resident slots >= 1250 blocks.
// ---------------------------------------------------------------------------
__global__ __launch_bounds__(256, 6) void mono_kernel(
        const float* __restrict__ x,      // [128][40000]
        const float* __restrict__ x0,     // [40000][128]
        const int*   __restrict__ e0,     // [40000][16]
        const bf16x8* __restrict__ WB,    // 64 frags x 64 lanes x 16B
        const float* __restrict__ bias,   // [128]
        unsigned* __restrict__ xTb,       // ws [N][64] u32 = bf16x2
        unsigned* __restrict__ flags,     // ws [1250]
        float*    __restrict__ out) {     // [128][40000]
    __shared__ unsigned y[32][132];       // [node][sum(64) | x0(64) | pad 4]
    __shared__ int eis[512];
    unsigned* tbuf = &y[0][0];            // 32*65 u32 alias (dead after store)

    const int b   = blockIdx.x;
    const int nb  = b * 32;
    const int tid = threadIdx.x;
    const int lane = tid & 63;
    const int wid  = tid >> 6;

    // edge indices early (separate LDS array; overlaps transpose loads)
    eis[tid]       = e0[(size_t)nb * K_NBR + tid];
    eis[256 + tid] = e0[(size_t)nb * K_NBR + 256 + tid];

    // ---- Produce: transpose+cast own tile (R7-proven pattern) ----
    {
        const int c2 = tid >> 2;          // 0..63
        const int h  = tid & 3;           // n-offset h*8
        const float* r0 = &x[(size_t)(2 * c2)     * N_NODES + nb + h * 8];
        const float* r1 = &x[(size_t)(2 * c2 + 1) * N_NODES + nb + h * 8];
        const float4 a0 = *(const float4*)(r0);
        const float4 a1 = *(const float4*)(r0 + 4);
        const float4 b0 = *(const float4*)(r1);
        const float4 b1 = *(const float4*)(r1 + 4);
        unsigned* lrow = &tbuf[h * 8 * 65 + c2];
        lrow[0 * 65] = pack_bf16x2(a0.x, b0.x);
        lrow[1 * 65] = pack_bf16x2(a0.y, b0.y);
        lrow[2 * 65] = pack_bf16x2(a0.z, b0.z);
        lrow[3 * 65] = pack_bf16x2(a0.w, b0.w);
        lrow[4 * 65] = pack_bf16x2(a1.x, b1.x);
        lrow[5 * 65] = pack_bf16x2(a1.y, b1.y);
        lrow[6 * 65] = pack_bf16x2(a1.z, b1.z);
        lrow[7 * 65] = pack_bf16x2(a1.w, b1.w);
    }
    __syncthreads();
    {
        const int n = tid >> 3, q = tid & 7;
        const unsigned* src = &tbuf[n * 65 + q * 8];
        unsigned* dst = &xTb[(size_t)(nb + n) * 64 + q * 8];
        *(uint4*)&dst[0] = make_uint4(src[0], src[1], src[2], src[3]);
        *(uint4*)&dst[4] = make_uint4(src[4], src[5], src[6], src[7]);
    }
    __syncthreads();                       // drains the xTb stores (vmcnt)
    __threadfence();                       // device-scope writeback
    if (tid == 0)
        __hip_atomic_store(&flags[b], 1u, __ATOMIC_RELEASE,
                           __HIP_MEMORY_SCOPE_AGENT);

    // ---- Consume: x0 stage (tbuf now dead; y cols 64+) ----
    const int node = tid >> 3;             // 0..31
    const int g8   = tid & 7;              // 0..7
    {
        const float* r = &x0[(size_t)(nb + node) * C_DIM + g8 * 16];
        const float4 v0 = *(const float4*)(r);
        const float4 v1 = *(const float4*)(r + 4);
        const float4 v2 = *(const float4*)(r + 8);
        const float4 v3 = *(const float4*)(r + 12);
        uint4 ua, ub;
        ua.x = pack_bf16x2(v0.x, v0.y);  ua.y = pack_bf16x2(v0.z, v0.w);
        ua.z = pack_bf16x2(v1.x, v1.y);  ua.w = pack_bf16x2(v1.z, v1.w);
        ub.x = pack_bf16x2(v2.x, v2.y);  ub.y = pack_bf16x2(v2.z, v2.w);
        ub.z = pack_bf16x2(v3.x, v3.y);  ub.w = pack_bf16x2(v3.z, v3.w);
        *(uint4*)&y[node][64 + g8 * 8]     = ua;
        *(uint4*)&y[node][64 + g8 * 8 + 4] = ub;
    }

    int jreg[K_NBR];
#pragma unroll
    for (int k = 0; k < K_NBR; ++k) jreg[k] = eis[node * K_NBR + k];

    // wait for the 17 source tiles (own tile produced above)
#pragma unroll 1
    for (int k = 0; k < K_NBR; ++k) {
        const int t = jreg[k] >> 5;
        while (__hip_atomic_load(&flags[t], __ATOMIC_RELAXED,
                                 __HIP_MEMORY_SCOPE_AGENT) == 0u) {
            __builtin_amdgcn_s_sleep(2);
        }
    }

    // ---- gather-sum in 4 channel-quarter passes (R11-proven best) ----
#pragma unroll 1
    for (int q = 0; q < 4; ++q) {
        const int off = q * 16 + 2 * g8;          // u32 offset within row
        const uint2 sv = *(const uint2*)&xTb[(size_t)(nb + node) * 64 + off];
        float s0 = bflo(sv.x), s1 = bfhi(sv.x);
        float s2 = bflo(sv.y), s3 = bfhi(sv.y);
#pragma unroll
        for (int k = 0; k < K_NBR; ++k) {
            const uint2 v = *(const uint2*)&xTb[(size_t)jreg[k] * 64 + off];
            s0 += bflo(v.x); s1 += bfhi(v.x);
            s2 += bflo(v.y); s3 += bfhi(v.y);
        }
        *(uint2*)&y[node][off] =
            make_uint2(pack_bf16x2(s0, s1), pack_bf16x2(s2, s3));
    }
    __syncthreads();

    // ---- MFMA GEMM (K=256) — unchanged from R11 ----
    const int nh = wid & 1;
    const int oh = wid >> 1;
    const int arow = nh * 16 + (lane & 15);
    const int acol = (lane >> 4) * 4;

    bf16x8 afrag[8];
#pragma unroll
    for (int kb = 0; kb < 8; ++kb)
        afrag[kb] = *(const bf16x8*)&y[arow][kb * 16 + acol];

    f32x4 acc[4];
#pragma unroll
    for (int t = 0; t < 4; ++t) {
        f32x4 a = {0.f, 0.f, 0.f, 0.f};
#pragma unroll
        for (int kb = 0; kb < 8; ++kb) {
            bf16x8 bv = WB[((oh * 4 + t) * 8 + kb) * 64 + lane];
            a = __builtin_amdgcn_mfma_f32_16x16x32_bf16(afrag[kb], bv, a, 0, 0, 0);
        }
        acc[t] = a;
    }

    // ---- relu(acc + bias), store [C][N] — unchanged ----
    const int rbase = nh * 16 + (lane >> 4) * 4;
#pragma unroll
    for (int t = 0; t < 4; ++t) {
        const int o = oh * 64 + t * 16 + (lane & 15);
        const float bo = bias[o];
        float4 res;
        res.x = fmaxf(acc[t][0] + bo, 0.0f);
        res.y = fmaxf(acc[t][1] + bo, 0.0f);
        res.z = fmaxf(acc[t][2] + bo, 0.0f);
        res.w = fmaxf(acc[t][3] + bo, 0.0f);
        *(float4*)&out[(size_t)o * N_NODES + nb + rbase] = res;
    }
}

// ---------------------------------------------------------------------------
extern "C" void kernel_launch(void* const* d_in, const int* in_sizes, int n_in,
                              void* d_out, int out_size, void* d_ws, size_t ws_size,
                              hipStream_t stream) {
    const float* x    = (const float*)d_in[0];   // [1,128,40000,1]
    const float* x0   = (const float*)d_in[1];   // [1,40000,128]
    const int*   ei   = (const int*)  d_in[2];   // [2,1,40000,16]; row 0
    const float* W1   = (const float*)d_in[3];   // [128,128]
    const float* W2   = (const float*)d_in[4];   // [128,128]
    const float* bias = (const float*)d_in[5];   // [128]
    float* out = (float*)d_out;                  // [1,128,40000,1]

    // ws: [0,64K) WB ; [64K,64K+8K) flags ; [72K, +10.24MB) xTb
    unsigned short* WB    = (unsigned short*)d_ws;
    unsigned*       flags = (unsigned*)((char*)d_ws + 65536);
    unsigned*       xTb   = (unsigned*)((char*)d_ws + 73728);

    hipMemsetAsync(flags, 0, 1250 * sizeof(unsigned), stream);
    hipLaunchKernelGGL(wprep_kernel, dim3(128), dim3(256), 0, stream,
                       W1, W2, WB);
    hipLaunchKernelGGL(mono_kernel, dim3(1250), dim3(256), 0, stream,
                       x, x0, ei, (const bf16x8*)WB, bias, xTb, flags, out);
}

// Round 18
// 40.652 us; speedup vs baseline: 5.6889x; 5.6889x over previous
//
#include <hip/hip_runtime.h>

#define N_NODES 40000
#define C_DIM   128
#define K_NBR   16

static constexpr float BETA_F  = 0.11778303565638346f;  // log(1.125)
static constexpr float C1_F    = 0.7939952679092549f;   // (1-ALPHA)*(1-BETA)
static constexpr float C2_F    = 0.08822169643436166f;  // ALPHA*(1-BETA)
static constexpr float INV_DEG = 1.0f / 17.0f;

typedef __attribute__((ext_vector_type(8))) short bf16x8;
typedef __attribute__((ext_vector_type(4))) float f32x4;

__device__ __forceinline__ unsigned pack_bf16x2(float a, float b) {
    unsigned ua = __float_as_uint(a), ub = __float_as_uint(b);
    ua += 0x7fffu + ((ua >> 16) & 1u);     // RNE
    ub += 0x7fffu + ((ub >> 16) & 1u);
    return (ua >> 16) | (ub & 0xffff0000u);
}
__device__ __forceinline__ float bflo(unsigned u) { return __uint_as_float(u << 16); }
__device__ __forceinline__ float bfhi(unsigned u) { return __uint_as_float(u & 0xffff0000u); }

// ---------------------------------------------------------------------------
// Kernel 1 (prep) — R7/R11 best-known: grid = 128 + 1250 blocks.
//   blocks 0..127    : folded-W fragment build (parallel, 1 elem/thread).
//   blocks 128..1377 : transpose+cast 32n x 128c of x -> xTb [N][64] u32.
// W'[c][o] = c<128 ? (BETA*W1[o][c] + (c==o)*C1) * INV_DEG
//                  : BETA*W2[o][c-128] + (c-128==o)*C2
// ---------------------------------------------------------------------------
__global__ __launch_bounds__(256) void prep_kernel(
        const float* __restrict__ x,
        const float* __restrict__ W1,
        const float* __restrict__ W2,
        unsigned* __restrict__ xTb,
        unsigned short* __restrict__ WB) {
    __shared__ unsigned lds[32 * 65];   // [n][c2], stride 65 u32 (8320 B)

    const int b = blockIdx.x;
    const int tid = threadIdx.x;

    if (b < 128) {
        const int i = b * 256 + tid;                   // 0 .. 32767
        const int frag = i >> 9, within = i & 511;
        const int lane = within >> 3, j = within & 7;
        const int otile = frag >> 3, kblk = frag & 7;
        const int o = otile * 16 + (lane & 15);
        const int c = kblk * 32 + ((lane >> 4) << 3) + j;
        float v;
        if (c < 128) {
            v = (BETA_F * W1[o * 128 + c] + (c == o ? C1_F : 0.0f)) * INV_DEG;
        } else {
            const int c2 = c - 128;
            v = BETA_F * W2[o * 128 + c2] + (c2 == o ? C2_F : 0.0f);
        }
        unsigned u = __float_as_uint(v);
        u += 0x7fffu + ((u >> 16) & 1u);
        WB[i] = (unsigned short)(u >> 16);
        return;
    }

    const int nb = (b - 128) * 32;

    const int c2 = tid >> 2;          // 0..63
    const int h  = tid & 3;           // n-offset h*8
    const float* r0 = &x[(size_t)(2 * c2)     * N_NODES + nb + h * 8];
    const float* r1 = &x[(size_t)(2 * c2 + 1) * N_NODES + nb + h * 8];
    const float4 a0 = *(const float4*)(r0);
    const float4 a1 = *(const float4*)(r0 + 4);
    const float4 b0 = *(const float4*)(r1);
    const float4 b1 = *(const float4*)(r1 + 4);

    unsigned* lrow = &lds[h * 8 * 65 + c2];
    lrow[0 * 65] = pack_bf16x2(a0.x, b0.x);
    lrow[1 * 65] = pack_bf16x2(a0.y, b0.y);
    lrow[2 * 65] = pack_bf16x2(a0.z, b0.z);
    lrow[3 * 65] = pack_bf16x2(a0.w, b0.w);
    lrow[4 * 65] = pack_bf16x2(a1.x, b1.x);
    lrow[5 * 65] = pack_bf16x2(a1.y, b1.y);
    lrow[6 * 65] = pack_bf16x2(a1.z, b1.z);
    lrow[7 * 65] = pack_bf16x2(a1.w, b1.w);
    __syncthreads();

    const int n = tid >> 3, q = tid & 7;
    const unsigned* src = &lds[n * 65 + q * 8];
    unsigned* dst = &xTb[(size_t)(nb + n) * 64 + q * 8];
    *(uint4*)&dst[0] = make_uint4(src[0], src[1], src[2], src[3]);
    *(uint4*)&dst[4] = make_uint4(src[4], src[5], src[6], src[7]);
}

// ---------------------------------------------------------------------------
// Kernel 2 (fused): gather-sum (4 channel-quarter passes, reg-hoisted
// indices) + MFMA GEMM (folded W') + relu/bias epilogue.
// Block = 256 threads (4 waves), 32 nodes/block, grid = 1250.
// ---------------------------------------------------------------------------
__global__ __launch_bounds__(256) void fused4_kernel(
        const unsigned* __restrict__ xTb,     // [N][64] u32 = bf16x2
        const float*    __restrict__ x0,      // [N][128] f32
        const int*      __restrict__ e0,      // [N][16]
        const bf16x8*   __restrict__ WB,      // 64 frags x 64 lanes x 16B
        const float*    __restrict__ bias,    // [128]
        float*          __restrict__ out) {   // [128][N]
    __shared__ unsigned y[32][132];           // [node][sum(64) | x0(64) | pad 4]
    __shared__ int eis[512];

    const int nb   = blockIdx.x * 32;
    const int tid  = threadIdx.x;
    const int lane = tid & 63;
    const int wid  = tid >> 6;

    eis[tid]       = e0[(size_t)nb * K_NBR + tid];
    eis[256 + tid] = e0[(size_t)nb * K_NBR + 256 + tid];
    __syncthreads();

    // ---- Phase 1a: stage x0 tile (bf16) — issued early, independent ----
    const int node = tid >> 3;        // 0..31
    const int g8   = tid & 7;         // 0..7
    {
        const float* r = &x0[(size_t)(nb + node) * C_DIM + g8 * 16];
        const float4 v0 = *(const float4*)(r);
        const float4 v1 = *(const float4*)(r + 4);
        const float4 v2 = *(const float4*)(r + 8);
        const float4 v3 = *(const float4*)(r + 12);
        uint4 ua, ub;
        ua.x = pack_bf16x2(v0.x, v0.y);  ua.y = pack_bf16x2(v0.z, v0.w);
        ua.z = pack_bf16x2(v1.x, v1.y);  ua.w = pack_bf16x2(v1.z, v1.w);
        ub.x = pack_bf16x2(v2.x, v2.y);  ub.y = pack_bf16x2(v2.z, v2.w);
        ub.z = pack_bf16x2(v3.x, v3.y);  ub.w = pack_bf16x2(v3.z, v3.w);
        *(uint4*)&y[node][64 + g8 * 8]     = ua;
        *(uint4*)&y[node][64 + g8 * 8 + 4] = ub;
    }

    // ---- Phase 1b: neighbor indices -> registers (statically indexed) ----
    int jreg[K_NBR];
#pragma unroll
    for (int k = 0; k < K_NBR; ++k) jreg[k] = eis[node * K_NBR + k];

    // ---- Phase 1c: gather-sum in 4 channel-quarter passes ----
#pragma unroll 1
    for (int q = 0; q < 4; ++q) {
        const int off = q * 16 + 2 * g8;          // u32 offset within row
        const uint2 sv = *(const uint2*)&xTb[(size_t)(nb + node) * 64 + off];
        float s0 = bflo(sv.x), s1 = bfhi(sv.x);
        float s2 = bflo(sv.y), s3 = bfhi(sv.y);
#pragma unroll
        for (int k = 0; k < K_NBR; ++k) {
            const uint2 v = *(const uint2*)&xTb[(size_t)jreg[k] * 64 + off];
            s0 += bflo(v.x); s1 += bfhi(v.x);
            s2 += bflo(v.y); s3 += bfhi(v.y);
        }
        *(uint2*)&y[node][off] =
            make_uint2(pack_bf16x2(s0, s1), pack_bf16x2(s2, s3));
    }
    __syncthreads();

    // ---- Phase 2: MFMA GEMM (K=256) ----
    const int nh = wid & 1;
    const int oh = wid >> 1;
    const int arow = nh * 16 + (lane & 15);
    const int acol = (lane >> 4) * 4;

    bf16x8 afrag[8];
#pragma unroll
    for (int kb = 0; kb < 8; ++kb)
        afrag[kb] = *(const bf16x8*)&y[arow][kb * 16 + acol];

    f32x4 acc[4];
#pragma unroll
    for (int t = 0; t < 4; ++t) {
        f32x4 a = {0.f, 0.f, 0.f, 0.f};
#pragma unroll
        for (int kb = 0; kb < 8; ++kb) {
            bf16x8 bv = WB[((oh * 4 + t) * 8 + kb) * 64 + lane];
            a = __builtin_amdgcn_mfma_f32_16x16x32_bf16(afrag[kb], bv, a, 0, 0, 0);
        }
        acc[t] = a;
    }

    // ---- Phase 3: relu(acc + bias), store [C][N] ----
    const int rbase = nh * 16 + (lane >> 4) * 4;
#pragma unroll
    for (int t = 0; t < 4; ++t) {
        const int o = oh * 64 + t * 16 + (lane & 15);
        const float bo = bias[o];
        float4 res;
        res.x = fmaxf(acc[t][0] + bo, 0.0f);
        res.y = fmaxf(acc[t][1] + bo, 0.0f);
        res.z = fmaxf(acc[t][2] + bo, 0.0f);
        res.w = fmaxf(acc[t][3] + bo, 0.0f);
        *(float4*)&out[(size_t)o * N_NODES + nb + rbase] = res;
    }
}

// ---------------------------------------------------------------------------
extern "C" void kernel_launch(void* const* d_in, const int* in_sizes, int n_in,
                              void* d_out, int out_size, void* d_ws, size_t ws_size,
                              hipStream_t stream) {
    const float* x    = (const float*)d_in[0];   // [1,128,40000,1]
    const float* x0   = (const float*)d_in[1];   // [1,40000,128]
    const int*   ei   = (const int*)  d_in[2];   // [2,1,40000,16]; row 0
    const float* W1   = (const float*)d_in[3];   // [128,128]
    const float* W2   = (const float*)d_in[4];   // [128,128]
    const float* bias = (const float*)d_in[5];   // [128]
    float* out = (float*)d_out;                  // [1,128,40000,1]

    // ws: [0, 64KB) WB' bf16 frags ; [64KB, 64KB+10.24MB) xTb
    unsigned short* WB  = (unsigned short*)d_ws;
    unsigned*       xTb = (unsigned*)((char*)d_ws + 65536);

    hipLaunchKernelGGL(prep_kernel, dim3(1378), dim3(256), 0, stream,
                       x, W1, W2, xTb, WB);
    hipLaunchKernelGGL(fused4_kernel, dim3(1250), dim3(256), 0, stream,
                       xTb, x0, ei, (const bf16x8*)WB, bias, out);
}